// Round 6
// baseline (437.997 us; speedup 1.0000x reference)
//
#include <hip/hip_runtime.h>
#include <math.h>

#define F 64
#define NPB 160        // nodes per bucket
#define STAGE_CAP 6304 // staged CSR entries per bucket (mean ~2720, +60 sigma)

// ---------------- bucketed CSR build ----------------

__global__ __launch_bounds__(256) void k_bin_count(const int* __restrict__ edst, int* __restrict__ cntT,
                                                   int e, int ch, int nblk, int nb) {
  __shared__ int h[1024];
  int k = blockIdx.x, tid = threadIdx.x;
  for (int i = tid; i < nb; i += 256) h[i] = 0;
  __syncthreads();
  int beg = k * ch, end = min(e, beg + ch);
  for (int i = beg + tid; i < end; i += 256) atomicAdd(&h[edst[i] / NPB], 1);
  __syncthreads();
  for (int b = tid; b < nb; b += 256) cntT[b * nblk + k] = h[b];
}

// per-256-block exclusive scan; block totals to bsums (global offset = posT[i] + bsums[i>>8])
__global__ __launch_bounds__(256) void k_scan1(const int* __restrict__ counts, int* __restrict__ offs,
                                               int* __restrict__ bsums, int n) {
  int tid = threadIdx.x, lane = tid & 63, wv = tid >> 6;
  int i = blockIdx.x * 256 + tid;
  int v = (i < n) ? counts[i] : 0;
  int x = v;
  #pragma unroll
  for (int o = 1; o <= 32; o <<= 1) { int y = __shfl_up(x, o); if (lane >= o) x += y; }
  __shared__ int wsum[4];
  if (lane == 63) wsum[wv] = x;
  __syncthreads();
  int add = 0;
  for (int w = 0; w < wv; w++) add += wsum[w];
  int incl = x + add;
  if (i < n) offs[i] = incl - v;
  if (tid == 255) bsums[blockIdx.x] = incl;
}

__global__ __launch_bounds__(256) void k_scan2(int* __restrict__ bs, int nb) {
  __shared__ int wsum[4];
  __shared__ int carry_sh;
  int tid = threadIdx.x, lane = tid & 63, wv = tid >> 6;
  if (tid == 0) carry_sh = 0;
  __syncthreads();
  for (int base = 0; base < nb; base += 256) {
    int i = base + tid;
    int v = (i < nb) ? bs[i] : 0;
    int x = v;
    #pragma unroll
    for (int o = 1; o <= 32; o <<= 1) { int y = __shfl_up(x, o); if (lane >= o) x += y; }
    if (lane == 63) wsum[wv] = x;
    __syncthreads();
    int add = 0;
    for (int w = 0; w < wv; w++) add += wsum[w];
    int incl = x + add;
    int carry = carry_sh;
    if (i < nb) bs[i] = incl - v + carry;
    __syncthreads();
    if (tid == 255) carry_sh = carry + incl;
    __syncthreads();
  }
}

__global__ __launch_bounds__(256) void k_bin_scatter(const int* __restrict__ esrc, const int* __restrict__ edst,
                                                     const int* __restrict__ posT, const int* __restrict__ bsums,
                                                     unsigned int* __restrict__ binned,
                                                     int e, int ch, int nblk, int nb) {
  __shared__ int cur[1024];
  int k = blockIdx.x, tid = threadIdx.x;
  for (int b = tid; b < nb; b += 256) {
    int idx = b * nblk + k;
    cur[b] = posT[idx] + bsums[idx >> 8];
  }
  __syncthreads();
  int beg = k * ch, end = min(e, beg + ch);
  for (int i = beg + tid; i < end; i += 256) {
    int d = edst[i];
    int b = d / NPB;
    unsigned int ld = (unsigned int)(d - b * NPB);
    int p = atomicAdd(&cur[b], 1);
    binned[p] = (unsigned int)esrc[i] | (ld << 24);
  }
}

// one block per bucket: build CSR rows (self-loop at row head), emit ssrc + offs
__global__ __launch_bounds__(256) void k_bucket_csr(const unsigned int* __restrict__ binned,
                                                    const int* __restrict__ posT, const int* __restrict__ bsums,
                                                    int* __restrict__ ssrc, int* __restrict__ offs,
                                                    int n, int nblk, int nb, int e) {
  __shared__ int ncnt[NPB];
  __shared__ int noff[NPB];
  __shared__ int cur[NPB];
  __shared__ int sc[256];
  __shared__ int stage[STAGE_CAP];
  int b = blockIdx.x, tid = threadIdx.x;
  int node0 = b * NPB;
  int nn = min(NPB, n - node0);
  int i0 = b * nblk;
  int ebeg = posT[i0] + bsums[i0 >> 8];
  int eend;
  if (b == nb - 1) eend = e;
  else { int i1 = (b + 1) * nblk; eend = posT[i1] + bsums[i1 >> 8]; }
  int ecnt = eend - ebeg;
  for (int i = tid; i < NPB; i += 256) ncnt[i] = 0;
  __syncthreads();
  for (int i = tid; i < ecnt; i += 256) { unsigned int v = binned[ebeg + i]; atomicAdd(&ncnt[v >> 24], 1); }
  __syncthreads();
  int x = (tid < nn) ? ncnt[tid] + 1 : 0;
  sc[tid] = x;
  __syncthreads();
  #pragma unroll
  for (int o = 1; o < 256; o <<= 1) {
    int y = (tid >= o) ? sc[tid - o] : 0;
    __syncthreads();
    sc[tid] += y;
    __syncthreads();
  }
  if (tid < nn) noff[tid] = sc[tid] - x;
  __syncthreads();
  int tot = ecnt + nn;
  int outbase = ebeg + node0;
  bool staged = (tot <= STAGE_CAP);
  if (tid < nn) {
    cur[tid] = noff[tid] + 1;
    offs[node0 + tid] = outbase + noff[tid];
    if (staged) stage[noff[tid]] = node0 + tid;
    else        ssrc[outbase + noff[tid]] = node0 + tid;
  }
  __syncthreads();
  if (staged) {
    for (int i = tid; i < ecnt; i += 256) {
      unsigned int v = binned[ebeg + i];
      int p = atomicAdd(&cur[v >> 24], 1);
      stage[p] = (int)(v & 0xFFFFFFu);
    }
    __syncthreads();
    for (int i = tid; i < tot; i += 256) ssrc[outbase + i] = stage[i];
  } else {
    for (int i = tid; i < ecnt; i += 256) {
      unsigned int v = binned[ebeg + i];
      int p = atomicAdd(&cur[v >> 24], 1);
      ssrc[outbase + p] = (int)(v & 0xFFFFFFu);
    }
  }
  if (b == 0 && tid == 0) offs[n] = e + n;
}

// ---------------- GEMM h = in @ W (64x64): bf16 h out, fp32 al_src/al_dst ----------------
// lane = output channel (W column in VGPRs); X rows read at wave-uniform addresses so the
// compiler emits scalar/broadcast loads — NO LDS staging, LDS pipe only carries the 2 reductions.
__global__ __launch_bounds__(256) void k_gemm(const float* __restrict__ in, const float* __restrict__ W,
                                              const float* __restrict__ avs, const float* __restrict__ avd,
                                              unsigned short* __restrict__ hgb, float* __restrict__ als,
                                              float* __restrict__ ald, int n) {
  int tid = threadIdx.x, lane = tid & 63;
  int wvu = __builtin_amdgcn_readfirstlane(tid >> 6);  // wave id as SGPR -> uniform addresses
  float wreg[F];
  #pragma unroll
  for (int k = 0; k < F; k++) wreg[k] = W[k * F + lane];
  float as = avs[lane], ad = avd[lane];
  int nchunks = n >> 6;
  for (int chunk = blockIdx.x; chunk < nchunks; chunk += gridDim.x) {
    int r0 = (chunk << 6) + (wvu << 4);
    #pragma unroll 2
    for (int rl = 0; rl < 16; rl++) {
      int r = r0 + rl;
      const float4* xr = (const float4*)(in + (size_t)r * F);  // uniform base
      float acc = 0.f;
      #pragma unroll
      for (int k4 = 0; k4 < 16; k4++) {
        float4 xk = xr[k4];                                    // s_load_dwordx4 (uniform)
        acc = fmaf(xk.x, wreg[k4 * 4 + 0], acc);
        acc = fmaf(xk.y, wreg[k4 * 4 + 1], acc);
        acc = fmaf(xk.z, wreg[k4 * 4 + 2], acc);
        acc = fmaf(xk.w, wreg[k4 * 4 + 3], acc);
      }
      // bf16 round-to-nearest-even
      unsigned int u = __float_as_uint(acc);
      u += 0x7fffu + ((u >> 16) & 1u);
      hgb[(size_t)r * F + lane] = (unsigned short)(u >> 16);
      float ps = acc * as, pd = acc * ad;
      #pragma unroll
      for (int o = 32; o >= 1; o >>= 1) { ps += __shfl_xor(ps, o); pd += __shfl_xor(pd, o); }
      if (lane == 0) { als[r] = ps; ald[r] = pd; }
    }
  }
}

// ---------------- fused softmax+SpMM, two-phase per wave ----------------
__global__ __launch_bounds__(256) void k_spmm(const int* __restrict__ offs, const int* __restrict__ ssrc,
                                              const unsigned short* __restrict__ hgb,
                                              const float* __restrict__ als, const float* __restrict__ ald,
                                              const float* __restrict__ bias, float* __restrict__ outp, int n) {
  __shared__ int2 exsh[4][64];
  int tid = threadIdx.x, lane = tid & 63, wv = tid >> 6;
  int g8 = lane >> 3, l8 = lane & 7;
  const uint4* hg4 = (const uint4*)hgb;
  float bch[8];
  #pragma unroll
  for (int k = 0; k < 8; k++) bch[k] = bias[l8 * 8 + k];
  int nwaves = gridDim.x * 4;
  for (int node = blockIdx.x * 4 + wv; node < n; node += nwaves) {
    int beg = offs[node], end = offs[node + 1];
    int deg = end - beg;
    float aldv = ald[node];
    float s = 0.f;
    float acc[8];
    #pragma unroll
    for (int k = 0; k < 8; k++) acc[k] = 0.f;
    for (int c0 = 0; c0 < deg; c0 += 64) {
      int nv = min(64, deg - c0);
      // phase A (no barrier: same-wave DS ordering)
      if (lane < nv) {
        int src = ssrc[beg + c0 + lane];
        float t = als[src] + aldv;
        t = (t >= 0.f) ? t : 0.2f * t;     // leaky_relu 0.2
        float ex = __expf(t);
        s += ex;
        exsh[wv][lane] = make_int2(src << 3, __float_as_int(ex));  // pre-scaled row offset
      }
      // phase B: full iterations (no predication)
      int full = nv >> 3;
      #pragma unroll 2
      for (int j8 = 0; j8 < full; j8++) {
        int2 pv = exsh[wv][(j8 << 3) + g8];
        float w = __int_as_float(pv.y);
        uint4 u = hg4[(size_t)pv.x + l8];
        acc[0] = fmaf(w, __uint_as_float(u.x << 16), acc[0]);
        acc[1] = fmaf(w, __uint_as_float(u.x & 0xffff0000u), acc[1]);
        acc[2] = fmaf(w, __uint_as_float(u.y << 16), acc[2]);
        acc[3] = fmaf(w, __uint_as_float(u.y & 0xffff0000u), acc[3]);
        acc[4] = fmaf(w, __uint_as_float(u.z << 16), acc[4]);
        acc[5] = fmaf(w, __uint_as_float(u.z & 0xffff0000u), acc[5]);
        acc[6] = fmaf(w, __uint_as_float(u.w << 16), acc[6]);
        acc[7] = fmaf(w, __uint_as_float(u.w & 0xffff0000u), acc[7]);
      }
      int rem = nv & 7;
      if (rem) {
        bool valid = g8 < rem;
        int2 pv = exsh[wv][valid ? (full << 3) + g8 : 0];
        float w = valid ? __int_as_float(pv.y) : 0.f;
        uint4 u = hg4[(size_t)pv.x + l8];
        acc[0] = fmaf(w, __uint_as_float(u.x << 16), acc[0]);
        acc[1] = fmaf(w, __uint_as_float(u.x & 0xffff0000u), acc[1]);
        acc[2] = fmaf(w, __uint_as_float(u.y << 16), acc[2]);
        acc[3] = fmaf(w, __uint_as_float(u.y & 0xffff0000u), acc[3]);
        acc[4] = fmaf(w, __uint_as_float(u.z << 16), acc[4]);
        acc[5] = fmaf(w, __uint_as_float(u.z & 0xffff0000u), acc[5]);
        acc[6] = fmaf(w, __uint_as_float(u.w << 16), acc[6]);
        acc[7] = fmaf(w, __uint_as_float(u.w & 0xffff0000u), acc[7]);
      }
    }
    #pragma unroll
    for (int o = 1; o <= 32; o <<= 1) s += __shfl_xor(s, o);
    #pragma unroll
    for (int o = 8; o <= 32; o <<= 1) {
      #pragma unroll
      for (int k = 0; k < 8; k++) acc[k] += __shfl_xor(acc[k], o);
    }
    if (g8 == 0) {
      float iv = 1.f / (s + 1e-16f);
      float4 r0, r1;
      r0.x = fmaxf(fmaf(acc[0], iv, bch[0]), 0.f);
      r0.y = fmaxf(fmaf(acc[1], iv, bch[1]), 0.f);
      r0.z = fmaxf(fmaf(acc[2], iv, bch[2]), 0.f);
      r0.w = fmaxf(fmaf(acc[3], iv, bch[3]), 0.f);
      r1.x = fmaxf(fmaf(acc[4], iv, bch[4]), 0.f);
      r1.y = fmaxf(fmaf(acc[5], iv, bch[5]), 0.f);
      r1.z = fmaxf(fmaf(acc[6], iv, bch[6]), 0.f);
      r1.w = fmaxf(fmaf(acc[7], iv, bch[7]), 0.f);
      float4* o4 = (float4*)outp + (size_t)node * 16 + l8 * 2;
      o4[0] = r0;
      o4[1] = r1;
    }
  }
}

// ---------------- final readout ----------------
__global__ __launch_bounds__(256) void k_final(const float* __restrict__ h, const float* __restrict__ Wout,
                                               const float* __restrict__ bout, float* __restrict__ out,
                                               int ng) {
  int tid = threadIdx.x, lane = tid & 63, wv = tid >> 6;
  int g = blockIdx.x * 4 + wv;
  if (g >= ng) return;
  const float4* h4 = (const float4*)h + (size_t)g * 320;
  const float4* w4 = (const float4*)Wout;
  float sacc = 0.f;
  #pragma unroll
  for (int k = 0; k < 5; k++) {
    float4 a = h4[k * 64 + lane];
    float4 b = w4[k * 64 + lane];
    sacc += a.x * b.x + a.y * b.y + a.z * b.z + a.w * b.w;
  }
  #pragma unroll
  for (int o = 32; o >= 1; o >>= 1) sacc += __shfl_xor(sacc, o);
  if (lane == 0) out[g] = sacc + bout[0];
}

// ---------------- launch ----------------
extern "C" void kernel_launch(void* const* d_in, const int* in_sizes, int n_in,
                              void* d_out, int out_size, void* d_ws, size_t ws_size,
                              hipStream_t stream) {
  const float* x   = (const float*)d_in[0];
  const int*   ei  = (const int*)d_in[1];
  const float* W1  = (const float*)d_in[2];
  const float* as1 = (const float*)d_in[3];
  const float* ad1 = (const float*)d_in[4];
  const float* b1  = (const float*)d_in[5];
  const float* W2  = (const float*)d_in[6];
  const float* as2 = (const float*)d_in[7];
  const float* ad2 = (const float*)d_in[8];
  const float* b2  = (const float*)d_in[9];
  const float* Wo  = (const float*)d_in[10];
  const float* bo  = (const float*)d_in[11];
  float* out = (float*)d_out;

  const int N = in_sizes[0] / F;
  const int E = in_sizes[1] / 2;
  const int* esrc = ei;
  const int* edst = ei + E;

  size_t off = 0;
  auto alloc = [&](size_t bytes) -> void* {
    void* p = (char*)d_ws + off;
    off += (bytes + 255) & ~(size_t)255;
    return p;
  };
  float* A    = (float*)alloc((size_t)N * F * 4);           // agg outputs (fp32); CSR cnt/pos scratch aliases head
  unsigned short* hgb = (unsigned short*)alloc((size_t)N * F * 2);  // bf16 gemm outputs; binned aliases head
  float* als  = (float*)alloc((size_t)N * 4);
  float* ald  = (float*)alloc((size_t)N * 4);
  int* offs   = (int*)alloc((size_t)(N + 1) * 4);
  int* bsums  = (int*)alloc(8192);
  int* ssrc   = (int*)alloc((size_t)(E + N) * 4);           // CSR src lists
  (void)ws_size; (void)n_in; (void)out_size;

  const int NBLK = 160;
  const int NB = (N + NPB - 1) / NPB;
  const int CH = (E + NBLK - 1) / NBLK;
  const int FLAT = NB * NBLK;

  int* cntT = (int*)A;
  int* posT = (int*)((char*)A + ((size_t)FLAT * 4 + 1024));
  unsigned int* binned = (unsigned int*)hgb;   // E uints <= N*F*2 bytes; dead before k_gemm writes hgb

  int gF = (FLAT + 255) / 256;

  // CSR build: bucketed counting sort (dst-major), self-loop at row head
  k_bin_count<<<NBLK, 256, 0, stream>>>(edst, cntT, E, CH, NBLK, NB);
  k_scan1<<<gF, 256, 0, stream>>>(cntT, posT, bsums, FLAT);
  k_scan2<<<1, 256, 0, stream>>>(bsums, gF);
  k_bin_scatter<<<NBLK, 256, 0, stream>>>(esrc, edst, posT, bsums, binned, E, CH, NBLK, NB);
  k_bucket_csr<<<NB, 256, 0, stream>>>(binned, posT, bsums, ssrc, offs, N, NBLK, NB, E);

  int gSp = 4096;  // persistent-ish: ~10 nodes per wave
  // layer 1
  k_gemm<<<1280, 256, 0, stream>>>(x, W1, as1, ad1, hgb, als, ald, N);
  k_spmm<<<gSp, 256, 0, stream>>>(offs, ssrc, hgb, als, ald, b1, A, N);
  // layer 2
  k_gemm<<<1280, 256, 0, stream>>>(A, W2, as2, ad2, hgb, als, ald, N);
  k_spmm<<<gSp, 256, 0, stream>>>(offs, ssrc, hgb, als, ald, b2, A, N);
  // readout
  int NG = N / 20;
  k_final<<<(NG + 3) / 4, 256, 0, stream>>>(A, Wo, bo, out, NG);
}

// Round 7
// 360.749 us; speedup vs baseline: 1.2141x; 1.2141x over previous
//
#include <hip/hip_runtime.h>
#include <math.h>

#define F 64
#define NPB 160        // nodes per bucket
#define STAGE_CAP 6304 // staged CSR entries per bucket (mean ~2720, +60 sigma)

typedef __attribute__((ext_vector_type(8))) short bf16x8;
typedef __attribute__((ext_vector_type(4))) float f32x4;

__device__ inline unsigned short f2bf(float f) {
  unsigned int u = __float_as_uint(f);
  u += 0x7fffu + ((u >> 16) & 1u);   // round-to-nearest-even
  return (unsigned short)(u >> 16);
}

// ---------------- bucketed CSR build ----------------

__global__ __launch_bounds__(256) void k_bin_count(const int* __restrict__ edst, int* __restrict__ cntT,
                                                   int e, int ch, int nblk, int nb) {
  __shared__ int h[1024];
  int k = blockIdx.x, tid = threadIdx.x;
  for (int i = tid; i < nb; i += 256) h[i] = 0;
  __syncthreads();
  int beg = k * ch, end = min(e, beg + ch);
  for (int i = beg + tid; i < end; i += 256) atomicAdd(&h[edst[i] / NPB], 1);
  __syncthreads();
  for (int b = tid; b < nb; b += 256) cntT[b * nblk + k] = h[b];
}

// per-256-block exclusive scan; block totals to bsums (global offset = posT[i] + bsums[i>>8])
__global__ __launch_bounds__(256) void k_scan1(const int* __restrict__ counts, int* __restrict__ offs,
                                               int* __restrict__ bsums, int n) {
  int tid = threadIdx.x, lane = tid & 63, wv = tid >> 6;
  int i = blockIdx.x * 256 + tid;
  int v = (i < n) ? counts[i] : 0;
  int x = v;
  #pragma unroll
  for (int o = 1; o <= 32; o <<= 1) { int y = __shfl_up(x, o); if (lane >= o) x += y; }
  __shared__ int wsum[4];
  if (lane == 63) wsum[wv] = x;
  __syncthreads();
  int add = 0;
  for (int w = 0; w < wv; w++) add += wsum[w];
  int incl = x + add;
  if (i < n) offs[i] = incl - v;
  if (tid == 255) bsums[blockIdx.x] = incl;
}

__global__ __launch_bounds__(256) void k_scan2(int* __restrict__ bs, int nb) {
  __shared__ int wsum[4];
  __shared__ int carry_sh;
  int tid = threadIdx.x, lane = tid & 63, wv = tid >> 6;
  if (tid == 0) carry_sh = 0;
  __syncthreads();
  for (int base = 0; base < nb; base += 256) {
    int i = base + tid;
    int v = (i < nb) ? bs[i] : 0;
    int x = v;
    #pragma unroll
    for (int o = 1; o <= 32; o <<= 1) { int y = __shfl_up(x, o); if (lane >= o) x += y; }
    if (lane == 63) wsum[wv] = x;
    __syncthreads();
    int add = 0;
    for (int w = 0; w < wv; w++) add += wsum[w];
    int incl = x + add;
    int carry = carry_sh;
    if (i < nb) bs[i] = incl - v + carry;
    __syncthreads();
    if (tid == 255) carry_sh = carry + incl;
    __syncthreads();
  }
}

__global__ __launch_bounds__(256) void k_bin_scatter(const int* __restrict__ esrc, const int* __restrict__ edst,
                                                     const int* __restrict__ posT, const int* __restrict__ bsums,
                                                     unsigned int* __restrict__ binned,
                                                     int e, int ch, int nblk, int nb) {
  __shared__ int cur[1024];
  int k = blockIdx.x, tid = threadIdx.x;
  for (int b = tid; b < nb; b += 256) {
    int idx = b * nblk + k;
    cur[b] = posT[idx] + bsums[idx >> 8];
  }
  __syncthreads();
  int beg = k * ch, end = min(e, beg + ch);
  for (int i = beg + tid; i < end; i += 256) {
    int d = edst[i];
    int b = d / NPB;
    unsigned int ld = (unsigned int)(d - b * NPB);
    int p = atomicAdd(&cur[b], 1);
    binned[p] = (unsigned int)esrc[i] | (ld << 24);
  }
}

// one block per bucket: build CSR rows (self-loop at row head), emit ssrc + offs
__global__ __launch_bounds__(256) void k_bucket_csr(const unsigned int* __restrict__ binned,
                                                    const int* __restrict__ posT, const int* __restrict__ bsums,
                                                    int* __restrict__ ssrc, int* __restrict__ offs,
                                                    int n, int nblk, int nb, int e) {
  __shared__ int ncnt[NPB];
  __shared__ int noff[NPB];
  __shared__ int cur[NPB];
  __shared__ int sc[256];
  __shared__ int stage[STAGE_CAP];
  int b = blockIdx.x, tid = threadIdx.x;
  int node0 = b * NPB;
  int nn = min(NPB, n - node0);
  int i0 = b * nblk;
  int ebeg = posT[i0] + bsums[i0 >> 8];
  int eend;
  if (b == nb - 1) eend = e;
  else { int i1 = (b + 1) * nblk; eend = posT[i1] + bsums[i1 >> 8]; }
  int ecnt = eend - ebeg;
  for (int i = tid; i < NPB; i += 256) ncnt[i] = 0;
  __syncthreads();
  for (int i = tid; i < ecnt; i += 256) { unsigned int v = binned[ebeg + i]; atomicAdd(&ncnt[v >> 24], 1); }
  __syncthreads();
  int x = (tid < nn) ? ncnt[tid] + 1 : 0;
  sc[tid] = x;
  __syncthreads();
  #pragma unroll
  for (int o = 1; o < 256; o <<= 1) {
    int y = (tid >= o) ? sc[tid - o] : 0;
    __syncthreads();
    sc[tid] += y;
    __syncthreads();
  }
  if (tid < nn) noff[tid] = sc[tid] - x;
  __syncthreads();
  int tot = ecnt + nn;
  int outbase = ebeg + node0;
  bool staged = (tot <= STAGE_CAP);
  if (tid < nn) {
    cur[tid] = noff[tid] + 1;
    offs[node0 + tid] = outbase + noff[tid];
    if (staged) stage[noff[tid]] = node0 + tid;
    else        ssrc[outbase + noff[tid]] = node0 + tid;
  }
  __syncthreads();
  if (staged) {
    for (int i = tid; i < ecnt; i += 256) {
      unsigned int v = binned[ebeg + i];
      int p = atomicAdd(&cur[v >> 24], 1);
      stage[p] = (int)(v & 0xFFFFFFu);
    }
    __syncthreads();
    for (int i = tid; i < tot; i += 256) ssrc[outbase + i] = stage[i];
  } else {
    for (int i = tid; i < ecnt; i += 256) {
      unsigned int v = binned[ebeg + i];
      int p = atomicAdd(&cur[v >> 24], 1);
      ssrc[outbase + p] = (int)(v & 0xFFFFFFu);
    }
  }
  if (b == 0 && tid == 0) offs[n] = e + n;
}

// ---------------- MFMA GEMM h = in @ W (64x64): bf16 h out, fp32 al_src/al_dst ----------------
// 16x16x32 bf16 MFMA. Per wave: 16 rows x 64 cols, K=64 -> 8 MFMA.
// A[m=lane&15][k=quad*8+j], B[k=quad*8+j][n=lane&15], D: col=lane&15, row=quad*4+reg.
__global__ __launch_bounds__(256) void k_gemm(const float* __restrict__ in, const float* __restrict__ W,
                                              const float* __restrict__ avs, const float* __restrict__ avd,
                                              unsigned short* __restrict__ hgb, float* __restrict__ als,
                                              float* __restrict__ ald, int n) {
  int tid = threadIdx.x, lane = tid & 63, wv = tid >> 6;
  int l15 = lane & 15, quad = lane >> 4;
  // B fragments: 4 col-chunks x 2 k-halves
  bf16x8 bfr[4][2];
  #pragma unroll
  for (int c = 0; c < 4; c++) {
    #pragma unroll
    for (int kk = 0; kk < 2; kk++) {
      #pragma unroll
      for (int j = 0; j < 8; j++) {
        int k = kk * 32 + quad * 8 + j;
        bfr[c][kk][j] = (short)f2bf(W[k * F + c * 16 + l15]);
      }
    }
  }
  float as_l[4], ad_l[4];
  #pragma unroll
  for (int c = 0; c < 4; c++) { as_l[c] = avs[c * 16 + l15]; ad_l[c] = avd[c * 16 + l15]; }

  int nchunks = n >> 6;
  for (int chunk = blockIdx.x; chunk < nchunks; chunk += gridDim.x) {
    int r0 = (chunk << 6) + (wv << 4);
    const float4* xr = (const float4*)(in + (size_t)(r0 + l15) * F + quad * 8);
    float4 xa = xr[0], xb = xr[1];   // k = quad*8 + 0..7
    float4 xc = xr[8], xd = xr[9];   // k = 32 + quad*8 + 0..7   (8 float4 = 32 floats)
    bf16x8 a0, a1;
    a0[0] = (short)f2bf(xa.x); a0[1] = (short)f2bf(xa.y); a0[2] = (short)f2bf(xa.z); a0[3] = (short)f2bf(xa.w);
    a0[4] = (short)f2bf(xb.x); a0[5] = (short)f2bf(xb.y); a0[6] = (short)f2bf(xb.z); a0[7] = (short)f2bf(xb.w);
    a1[0] = (short)f2bf(xc.x); a1[1] = (short)f2bf(xc.y); a1[2] = (short)f2bf(xc.z); a1[3] = (short)f2bf(xc.w);
    a1[4] = (short)f2bf(xd.x); a1[5] = (short)f2bf(xd.y); a1[6] = (short)f2bf(xd.z); a1[7] = (short)f2bf(xd.w);
    f32x4 cfr[4];
    #pragma unroll
    for (int c = 0; c < 4; c++) {
      cfr[c] = (f32x4){0.f, 0.f, 0.f, 0.f};
      cfr[c] = __builtin_amdgcn_mfma_f32_16x16x32_bf16(a0, bfr[c][0], cfr[c], 0, 0, 0);
      cfr[c] = __builtin_amdgcn_mfma_f32_16x16x32_bf16(a1, bfr[c][1], cfr[c], 0, 0, 0);
    }
    #pragma unroll
    for (int i = 0; i < 4; i++) {
      int row = r0 + quad * 4 + i;
      #pragma unroll
      for (int c = 0; c < 4; c++) hgb[(size_t)row * F + c * 16 + l15] = f2bf(cfr[c][i]);
      float ps = cfr[0][i] * as_l[0] + cfr[1][i] * as_l[1] + cfr[2][i] * as_l[2] + cfr[3][i] * as_l[3];
      float pd = cfr[0][i] * ad_l[0] + cfr[1][i] * ad_l[1] + cfr[2][i] * ad_l[2] + cfr[3][i] * ad_l[3];
      #pragma unroll
      for (int o = 1; o <= 8; o <<= 1) { ps += __shfl_xor(ps, o); pd += __shfl_xor(pd, o); }
      if (l15 == 0) { als[row] = ps; ald[row] = pd; }
    }
  }
}

// ---------------- fused softmax+SpMM, two-phase per wave ----------------
__global__ __launch_bounds__(256) void k_spmm(const int* __restrict__ offs, const int* __restrict__ ssrc,
                                              const unsigned short* __restrict__ hgb,
                                              const float* __restrict__ als, const float* __restrict__ ald,
                                              const float* __restrict__ bias, float* __restrict__ outp, int n) {
  __shared__ int2 exsh[4][64];
  int tid = threadIdx.x, lane = tid & 63, wv = tid >> 6;
  int g8 = lane >> 3, l8 = lane & 7;
  const uint4* hg4 = (const uint4*)hgb;
  float bch[8];
  #pragma unroll
  for (int k = 0; k < 8; k++) bch[k] = bias[l8 * 8 + k];
  int nwaves = gridDim.x * 4;
  for (int node = blockIdx.x * 4 + wv; node < n; node += nwaves) {
    int beg = offs[node], end = offs[node + 1];
    int deg = end - beg;
    float aldv = ald[node];
    float s = 0.f;
    float acc[8];
    #pragma unroll
    for (int k = 0; k < 8; k++) acc[k] = 0.f;
    for (int c0 = 0; c0 < deg; c0 += 64) {
      int nv = min(64, deg - c0);
      if (lane < nv) {
        int src = ssrc[beg + c0 + lane];
        float t = als[src] + aldv;
        t = (t >= 0.f) ? t : 0.2f * t;     // leaky_relu 0.2
        float ex = __expf(t);
        s += ex;
        exsh[wv][lane] = make_int2(src << 3, __float_as_int(ex));
      }
      int full = nv >> 3;
      #pragma unroll 2
      for (int j8 = 0; j8 < full; j8++) {
        int2 pv = exsh[wv][(j8 << 3) + g8];
        float w = __int_as_float(pv.y);
        uint4 u = hg4[(size_t)pv.x + l8];
        acc[0] = fmaf(w, __uint_as_float(u.x << 16), acc[0]);
        acc[1] = fmaf(w, __uint_as_float(u.x & 0xffff0000u), acc[1]);
        acc[2] = fmaf(w, __uint_as_float(u.y << 16), acc[2]);
        acc[3] = fmaf(w, __uint_as_float(u.y & 0xffff0000u), acc[3]);
        acc[4] = fmaf(w, __uint_as_float(u.z << 16), acc[4]);
        acc[5] = fmaf(w, __uint_as_float(u.z & 0xffff0000u), acc[5]);
        acc[6] = fmaf(w, __uint_as_float(u.w << 16), acc[6]);
        acc[7] = fmaf(w, __uint_as_float(u.w & 0xffff0000u), acc[7]);
      }
      int rem = nv & 7;
      if (rem) {
        bool valid = g8 < rem;
        int2 pv = exsh[wv][valid ? (full << 3) + g8 : 0];
        float w = valid ? __int_as_float(pv.y) : 0.f;
        uint4 u = hg4[(size_t)pv.x + l8];
        acc[0] = fmaf(w, __uint_as_float(u.x << 16), acc[0]);
        acc[1] = fmaf(w, __uint_as_float(u.x & 0xffff0000u), acc[1]);
        acc[2] = fmaf(w, __uint_as_float(u.y << 16), acc[2]);
        acc[3] = fmaf(w, __uint_as_float(u.y & 0xffff0000u), acc[3]);
        acc[4] = fmaf(w, __uint_as_float(u.z << 16), acc[4]);
        acc[5] = fmaf(w, __uint_as_float(u.z & 0xffff0000u), acc[5]);
        acc[6] = fmaf(w, __uint_as_float(u.w << 16), acc[6]);
        acc[7] = fmaf(w, __uint_as_float(u.w & 0xffff0000u), acc[7]);
      }
    }
    #pragma unroll
    for (int o = 1; o <= 32; o <<= 1) s += __shfl_xor(s, o);
    #pragma unroll
    for (int o = 8; o <= 32; o <<= 1) {
      #pragma unroll
      for (int k = 0; k < 8; k++) acc[k] += __shfl_xor(acc[k], o);
    }
    if (g8 == 0) {
      float iv = 1.f / (s + 1e-16f);
      float4 r0, r1;
      r0.x = fmaxf(fmaf(acc[0], iv, bch[0]), 0.f);
      r0.y = fmaxf(fmaf(acc[1], iv, bch[1]), 0.f);
      r0.z = fmaxf(fmaf(acc[2], iv, bch[2]), 0.f);
      r0.w = fmaxf(fmaf(acc[3], iv, bch[3]), 0.f);
      r1.x = fmaxf(fmaf(acc[4], iv, bch[4]), 0.f);
      r1.y = fmaxf(fmaf(acc[5], iv, bch[5]), 0.f);
      r1.z = fmaxf(fmaf(acc[6], iv, bch[6]), 0.f);
      r1.w = fmaxf(fmaf(acc[7], iv, bch[7]), 0.f);
      float4* o4 = (float4*)outp + (size_t)node * 16 + l8 * 2;
      o4[0] = r0;
      o4[1] = r1;
    }
  }
}

// ---------------- final readout ----------------
__global__ __launch_bounds__(256) void k_final(const float* __restrict__ h, const float* __restrict__ Wout,
                                               const float* __restrict__ bout, float* __restrict__ out,
                                               int ng) {
  int tid = threadIdx.x, lane = tid & 63, wv = tid >> 6;
  int g = blockIdx.x * 4 + wv;
  if (g >= ng) return;
  const float4* h4 = (const float4*)h + (size_t)g * 320;
  const float4* w4 = (const float4*)Wout;
  float sacc = 0.f;
  #pragma unroll
  for (int k = 0; k < 5; k++) {
    float4 a = h4[k * 64 + lane];
    float4 b = w4[k * 64 + lane];
    sacc += a.x * b.x + a.y * b.y + a.z * b.z + a.w * b.w;
  }
  #pragma unroll
  for (int o = 32; o >= 1; o >>= 1) sacc += __shfl_xor(sacc, o);
  if (lane == 0) out[g] = sacc + bout[0];
}

// ---------------- launch ----------------
extern "C" void kernel_launch(void* const* d_in, const int* in_sizes, int n_in,
                              void* d_out, int out_size, void* d_ws, size_t ws_size,
                              hipStream_t stream) {
  const float* x   = (const float*)d_in[0];
  const int*   ei  = (const int*)d_in[1];
  const float* W1  = (const float*)d_in[2];
  const float* as1 = (const float*)d_in[3];
  const float* ad1 = (const float*)d_in[4];
  const float* b1  = (const float*)d_in[5];
  const float* W2  = (const float*)d_in[6];
  const float* as2 = (const float*)d_in[7];
  const float* ad2 = (const float*)d_in[8];
  const float* b2  = (const float*)d_in[9];
  const float* Wo  = (const float*)d_in[10];
  const float* bo  = (const float*)d_in[11];
  float* out = (float*)d_out;

  const int N = in_sizes[0] / F;
  const int E = in_sizes[1] / 2;
  const int* esrc = ei;
  const int* edst = ei + E;

  size_t off = 0;
  auto alloc = [&](size_t bytes) -> void* {
    void* p = (char*)d_ws + off;
    off += (bytes + 255) & ~(size_t)255;
    return p;
  };
  float* A    = (float*)alloc((size_t)N * F * 4);           // agg outputs (fp32); CSR cnt/pos scratch aliases head
  unsigned short* hgb = (unsigned short*)alloc((size_t)N * F * 2);  // bf16 gemm outputs; binned aliases head
  float* als  = (float*)alloc((size_t)N * 4);
  float* ald  = (float*)alloc((size_t)N * 4);
  int* offs   = (int*)alloc((size_t)(N + 1) * 4);
  int* bsums  = (int*)alloc(8192);
  int* ssrc   = (int*)alloc((size_t)(E + N) * 4);           // CSR src lists
  (void)ws_size; (void)n_in; (void)out_size;

  const int NBLK = 160;
  const int NB = (N + NPB - 1) / NPB;
  const int CH = (E + NBLK - 1) / NBLK;
  const int FLAT = NB * NBLK;

  int* cntT = (int*)A;
  int* posT = (int*)((char*)A + ((size_t)FLAT * 4 + 1024));
  unsigned int* binned = (unsigned int*)hgb;   // E uints <= N*F*2 bytes; dead before k_gemm writes hgb

  int gF = (FLAT + 255) / 256;

  // CSR build: bucketed counting sort (dst-major), self-loop at row head
  k_bin_count<<<NBLK, 256, 0, stream>>>(edst, cntT, E, CH, NBLK, NB);
  k_scan1<<<gF, 256, 0, stream>>>(cntT, posT, bsums, FLAT);
  k_scan2<<<1, 256, 0, stream>>>(bsums, gF);
  k_bin_scatter<<<NBLK, 256, 0, stream>>>(esrc, edst, posT, bsums, binned, E, CH, NBLK, NB);
  k_bucket_csr<<<NB, 256, 0, stream>>>(binned, posT, bsums, ssrc, offs, N, NBLK, NB, E);

  int gSp = 4096;  // persistent-ish: ~10 nodes per wave
  // layer 1
  k_gemm<<<2560, 256, 0, stream>>>(x, W1, as1, ad1, hgb, als, ald, N);
  k_spmm<<<gSp, 256, 0, stream>>>(offs, ssrc, hgb, als, ald, b1, A, N);
  // layer 2
  k_gemm<<<2560, 256, 0, stream>>>(A, W2, as2, ad2, hgb, als, ald, N);
  k_spmm<<<gSp, 256, 0, stream>>>(offs, ssrc, hgb, als, ald, b2, A, N);
  // readout
  int NG = N / 20;
  k_final<<<(NG + 3) / 4, 256, 0, stream>>>(A, Wo, bo, out, NG);
}

// Round 8
// 318.311 us; speedup vs baseline: 1.3760x; 1.1333x over previous
//
#include <hip/hip_runtime.h>
#include <math.h>

#define F 64
#define NPB 160        // nodes per bucket
#define STAGE_CAP 6304 // staged CSR entries per bucket (mean ~2720, +60 sigma)

typedef __attribute__((ext_vector_type(8))) short bf16x8;
typedef __attribute__((ext_vector_type(4))) float f32x4;

__device__ inline unsigned short f2bf(float f) {
  unsigned int u = __float_as_uint(f);
  u += 0x7fffu + ((u >> 16) & 1u);   // round-to-nearest-even
  return (unsigned short)(u >> 16);
}

// ---------------- bucketed CSR build ----------------

__global__ __launch_bounds__(256) void k_bin_count(const int* __restrict__ edst, int* __restrict__ cntT,
                                                   int e, int ch, int nblk, int nb) {
  __shared__ int h[1024];
  int k = blockIdx.x, tid = threadIdx.x;
  for (int i = tid; i < nb; i += 256) h[i] = 0;
  __syncthreads();
  int beg = k * ch, end = min(e, beg + ch);
  for (int i = beg + tid; i < end; i += 256) atomicAdd(&h[edst[i] / NPB], 1);
  __syncthreads();
  for (int b = tid; b < nb; b += 256) cntT[b * nblk + k] = h[b];
}

// per-256-block exclusive scan; block totals to bsums (global offset = posT[i] + bsums[i>>8])
__global__ __launch_bounds__(256) void k_scan1(const int* __restrict__ counts, int* __restrict__ offs,
                                               int* __restrict__ bsums, int n) {
  int tid = threadIdx.x, lane = tid & 63, wv = tid >> 6;
  int i = blockIdx.x * 256 + tid;
  int v = (i < n) ? counts[i] : 0;
  int x = v;
  #pragma unroll
  for (int o = 1; o <= 32; o <<= 1) { int y = __shfl_up(x, o); if (lane >= o) x += y; }
  __shared__ int wsum[4];
  if (lane == 63) wsum[wv] = x;
  __syncthreads();
  int add = 0;
  for (int w = 0; w < wv; w++) add += wsum[w];
  int incl = x + add;
  if (i < n) offs[i] = incl - v;
  if (tid == 255) bsums[blockIdx.x] = incl;
}

__global__ __launch_bounds__(256) void k_scan2(int* __restrict__ bs, int nb) {
  __shared__ int wsum[4];
  __shared__ int carry_sh;
  int tid = threadIdx.x, lane = tid & 63, wv = tid >> 6;
  if (tid == 0) carry_sh = 0;
  __syncthreads();
  for (int base = 0; base < nb; base += 256) {
    int i = base + tid;
    int v = (i < nb) ? bs[i] : 0;
    int x = v;
    #pragma unroll
    for (int o = 1; o <= 32; o <<= 1) { int y = __shfl_up(x, o); if (lane >= o) x += y; }
    if (lane == 63) wsum[wv] = x;
    __syncthreads();
    int add = 0;
    for (int w = 0; w < wv; w++) add += wsum[w];
    int incl = x + add;
    int carry = carry_sh;
    if (i < nb) bs[i] = incl - v + carry;
    __syncthreads();
    if (tid == 255) carry_sh = carry + incl;
    __syncthreads();
  }
}

__global__ __launch_bounds__(256) void k_bin_scatter(const int* __restrict__ esrc, const int* __restrict__ edst,
                                                     const int* __restrict__ posT, const int* __restrict__ bsums,
                                                     unsigned int* __restrict__ binned,
                                                     int e, int ch, int nblk, int nb) {
  __shared__ int cur[1024];
  int k = blockIdx.x, tid = threadIdx.x;
  for (int b = tid; b < nb; b += 256) {
    int idx = b * nblk + k;
    cur[b] = posT[idx] + bsums[idx >> 8];
  }
  __syncthreads();
  int beg = k * ch, end = min(e, beg + ch);
  for (int i = beg + tid; i < end; i += 256) {
    int d = edst[i];
    int b = d / NPB;
    unsigned int ld = (unsigned int)(d - b * NPB);
    int p = atomicAdd(&cur[b], 1);
    binned[p] = (unsigned int)esrc[i] | (ld << 24);
  }
}

// one block per bucket: build CSR rows (self-loop at row head), emit ssrc + offs
__global__ __launch_bounds__(256) void k_bucket_csr(const unsigned int* __restrict__ binned,
                                                    const int* __restrict__ posT, const int* __restrict__ bsums,
                                                    int* __restrict__ ssrc, int* __restrict__ offs,
                                                    int n, int nblk, int nb, int e) {
  __shared__ int ncnt[NPB];
  __shared__ int noff[NPB];
  __shared__ int cur[NPB];
  __shared__ int sc[256];
  __shared__ int stage[STAGE_CAP];
  int b = blockIdx.x, tid = threadIdx.x;
  int node0 = b * NPB;
  int nn = min(NPB, n - node0);
  int i0 = b * nblk;
  int ebeg = posT[i0] + bsums[i0 >> 8];
  int eend;
  if (b == nb - 1) eend = e;
  else { int i1 = (b + 1) * nblk; eend = posT[i1] + bsums[i1 >> 8]; }
  int ecnt = eend - ebeg;
  for (int i = tid; i < NPB; i += 256) ncnt[i] = 0;
  __syncthreads();
  for (int i = tid; i < ecnt; i += 256) { unsigned int v = binned[ebeg + i]; atomicAdd(&ncnt[v >> 24], 1); }
  __syncthreads();
  int x = (tid < nn) ? ncnt[tid] + 1 : 0;
  sc[tid] = x;
  __syncthreads();
  #pragma unroll
  for (int o = 1; o < 256; o <<= 1) {
    int y = (tid >= o) ? sc[tid - o] : 0;
    __syncthreads();
    sc[tid] += y;
    __syncthreads();
  }
  if (tid < nn) noff[tid] = sc[tid] - x;
  __syncthreads();
  int tot = ecnt + nn;
  int outbase = ebeg + node0;
  bool staged = (tot <= STAGE_CAP);
  if (tid < nn) {
    cur[tid] = noff[tid] + 1;
    offs[node0 + tid] = outbase + noff[tid];
    if (staged) stage[noff[tid]] = node0 + tid;
    else        ssrc[outbase + noff[tid]] = node0 + tid;
  }
  __syncthreads();
  if (staged) {
    for (int i = tid; i < ecnt; i += 256) {
      unsigned int v = binned[ebeg + i];
      int p = atomicAdd(&cur[v >> 24], 1);
      stage[p] = (int)(v & 0xFFFFFFu);
    }
    __syncthreads();
    for (int i = tid; i < tot; i += 256) ssrc[outbase + i] = stage[i];
  } else {
    for (int i = tid; i < ecnt; i += 256) {
      unsigned int v = binned[ebeg + i];
      int p = atomicAdd(&cur[v >> 24], 1);
      ssrc[outbase + p] = (int)(v & 0xFFFFFFu);
    }
  }
  if (b == 0 && tid == 0) offs[n] = e + n;
}

// ---------------- MFMA GEMM h = in @ W (64x64): bf16 h out, fp32 al_src/al_dst ----------------
// 16x16x32 bf16 MFMA. Per wave: 16 rows x 64 cols, K=64 -> 8 MFMA.
// A[m=lane&15][k=quad*8+j], B[k=quad*8+j][n=lane&15], D: col=lane&15, row=quad*4+reg.
template<bool IN_BF16>
__global__ __launch_bounds__(256) void k_gemm(const void* __restrict__ in, const float* __restrict__ W,
                                              const float* __restrict__ avs, const float* __restrict__ avd,
                                              unsigned short* __restrict__ hgb, float* __restrict__ als,
                                              float* __restrict__ ald, int n) {
  int tid = threadIdx.x, lane = tid & 63, wv = tid >> 6;
  int l15 = lane & 15, quad = lane >> 4;
  bf16x8 bfr[4][2];
  #pragma unroll
  for (int c = 0; c < 4; c++) {
    #pragma unroll
    for (int kk = 0; kk < 2; kk++) {
      #pragma unroll
      for (int j = 0; j < 8; j++) {
        int k = kk * 32 + quad * 8 + j;
        bfr[c][kk][j] = (short)f2bf(W[k * F + c * 16 + l15]);
      }
    }
  }
  float as_l[4], ad_l[4];
  #pragma unroll
  for (int c = 0; c < 4; c++) { as_l[c] = avs[c * 16 + l15]; ad_l[c] = avd[c * 16 + l15]; }

  int nchunks = n >> 6;
  for (int chunk = blockIdx.x; chunk < nchunks; chunk += gridDim.x) {
    int r0 = (chunk << 6) + (wv << 4);
    bf16x8 a0, a1;
    if constexpr (IN_BF16) {
      const uint4* row4 = (const uint4*)((const unsigned short*)in + (size_t)(r0 + l15) * F);
      uint4 u0 = row4[quad];       // k = quad*8 + 0..7
      uint4 u1 = row4[quad + 4];   // k = 32 + quad*8 + 0..7
      a0 = *(const bf16x8*)&u0;
      a1 = *(const bf16x8*)&u1;
    } else {
      const float4* xr = (const float4*)((const float*)in + (size_t)(r0 + l15) * F + quad * 8);
      float4 xa = xr[0], xb = xr[1];
      float4 xc = xr[8], xd = xr[9];
      a0[0] = (short)f2bf(xa.x); a0[1] = (short)f2bf(xa.y); a0[2] = (short)f2bf(xa.z); a0[3] = (short)f2bf(xa.w);
      a0[4] = (short)f2bf(xb.x); a0[5] = (short)f2bf(xb.y); a0[6] = (short)f2bf(xb.z); a0[7] = (short)f2bf(xb.w);
      a1[0] = (short)f2bf(xc.x); a1[1] = (short)f2bf(xc.y); a1[2] = (short)f2bf(xc.z); a1[3] = (short)f2bf(xc.w);
      a1[4] = (short)f2bf(xd.x); a1[5] = (short)f2bf(xd.y); a1[6] = (short)f2bf(xd.z); a1[7] = (short)f2bf(xd.w);
    }
    f32x4 cfr[4];
    #pragma unroll
    for (int c = 0; c < 4; c++) {
      cfr[c] = (f32x4){0.f, 0.f, 0.f, 0.f};
      cfr[c] = __builtin_amdgcn_mfma_f32_16x16x32_bf16(a0, bfr[c][0], cfr[c], 0, 0, 0);
      cfr[c] = __builtin_amdgcn_mfma_f32_16x16x32_bf16(a1, bfr[c][1], cfr[c], 0, 0, 0);
    }
    #pragma unroll
    for (int i = 0; i < 4; i++) {
      int row = r0 + quad * 4 + i;
      #pragma unroll
      for (int c = 0; c < 4; c++) hgb[(size_t)row * F + c * 16 + l15] = f2bf(cfr[c][i]);
      float ps = cfr[0][i] * as_l[0] + cfr[1][i] * as_l[1] + cfr[2][i] * as_l[2] + cfr[3][i] * as_l[3];
      float pd = cfr[0][i] * ad_l[0] + cfr[1][i] * ad_l[1] + cfr[2][i] * ad_l[2] + cfr[3][i] * ad_l[3];
      #pragma unroll
      for (int o = 1; o <= 8; o <<= 1) { ps += __shfl_xor(ps, o); pd += __shfl_xor(pd, o); }
      if (l15 == 0) { als[row] = ps; ald[row] = pd; }
    }
  }
}

// ---------------- fused softmax+SpMM, node-per-subgroup ----------------
// 8 subgroups of 8 lanes per wave; subgroup g owns node wbase+g; lane l8 owns channels l8*8..+7.
// No cross-lane reductions: acc is final per lane, s replicated within subgroup.
template<bool OUT_BF16>
__global__ __launch_bounds__(256) void k_spmm(const int* __restrict__ offs, const int* __restrict__ ssrc,
                                              const unsigned short* __restrict__ hgb,
                                              const float* __restrict__ als, const float* __restrict__ ald,
                                              const float* __restrict__ bias, void* __restrict__ outp, int n) {
  int tid = threadIdx.x, lane = tid & 63, wv = tid >> 6;
  int g8 = lane >> 3, l8 = lane & 7;
  const uint4* hg4 = (const uint4*)hgb;
  float4 bl0 = ((const float4*)bias)[l8 * 2];
  float4 bl1 = ((const float4*)bias)[l8 * 2 + 1];

  int node = (blockIdx.x * 4 + wv) * 8 + g8;   // grid sized for exact cover
  int cnode = min(node, n - 1);
  bool nodeok = node < n;
  int beg = offs[cnode];
  int deg = nodeok ? (offs[cnode + 1] - beg) : 0;
  int degc = max(deg - 1, 0);
  float aldv = ald[cnode];

  // wave-max degree (all lanes valid)
  int dm = deg;
  #pragma unroll
  for (int o = 8; o <= 32; o <<= 1) dm = max(dm, __shfl_xor(dm, o));

  float s = 0.f;
  float acc[8];
  #pragma unroll
  for (int k = 0; k < 8; k++) acc[k] = 0.f;

  #pragma unroll 2
  for (int j = 0; j < dm; j++) {
    int jj = min(j, degc);
    int src = ssrc[beg + jj];                 // broadcast within subgroup
    float t = als[src] + aldv;                // 8 distinct lines/wave
    t = fmaxf(t, 0.2f * t);                   // leaky_relu 0.2
    float ex = (j < deg) ? __expf(t) : 0.f;
    s += ex;
    uint4 u = hg4[(size_t)src * 8 + l8];      // 8 rows x 16B per wave-instr
    acc[0] = fmaf(ex, __uint_as_float(u.x << 16), acc[0]);
    acc[1] = fmaf(ex, __uint_as_float(u.x & 0xffff0000u), acc[1]);
    acc[2] = fmaf(ex, __uint_as_float(u.y << 16), acc[2]);
    acc[3] = fmaf(ex, __uint_as_float(u.y & 0xffff0000u), acc[3]);
    acc[4] = fmaf(ex, __uint_as_float(u.z << 16), acc[4]);
    acc[5] = fmaf(ex, __uint_as_float(u.z & 0xffff0000u), acc[5]);
    acc[6] = fmaf(ex, __uint_as_float(u.w << 16), acc[6]);
    acc[7] = fmaf(ex, __uint_as_float(u.w & 0xffff0000u), acc[7]);
  }

  if (nodeok) {
    float iv = 1.f / (s + 1e-16f);
    float r[8];
    r[0] = fmaxf(fmaf(acc[0], iv, bl0.x), 0.f);
    r[1] = fmaxf(fmaf(acc[1], iv, bl0.y), 0.f);
    r[2] = fmaxf(fmaf(acc[2], iv, bl0.z), 0.f);
    r[3] = fmaxf(fmaf(acc[3], iv, bl0.w), 0.f);
    r[4] = fmaxf(fmaf(acc[4], iv, bl1.x), 0.f);
    r[5] = fmaxf(fmaf(acc[5], iv, bl1.y), 0.f);
    r[6] = fmaxf(fmaf(acc[6], iv, bl1.z), 0.f);
    r[7] = fmaxf(fmaf(acc[7], iv, bl1.w), 0.f);
    if constexpr (OUT_BF16) {
      unsigned short p[8];
      #pragma unroll
      for (int k = 0; k < 8; k++) p[k] = f2bf(r[k]);
      ((uint4*)outp)[(size_t)node * 8 + l8] = *(const uint4*)p;
    } else {
      float4* o4 = (float4*)outp + (size_t)node * 16 + l8 * 2;
      o4[0] = make_float4(r[0], r[1], r[2], r[3]);
      o4[1] = make_float4(r[4], r[5], r[6], r[7]);
    }
  }
}

// ---------------- final readout ----------------
__global__ __launch_bounds__(256) void k_final(const float* __restrict__ h, const float* __restrict__ Wout,
                                               const float* __restrict__ bout, float* __restrict__ out,
                                               int ng) {
  int tid = threadIdx.x, lane = tid & 63, wv = tid >> 6;
  int g = blockIdx.x * 4 + wv;
  if (g >= ng) return;
  const float4* h4 = (const float4*)h + (size_t)g * 320;
  const float4* w4 = (const float4*)Wout;
  float sacc = 0.f;
  #pragma unroll
  for (int k = 0; k < 5; k++) {
    float4 a = h4[k * 64 + lane];
    float4 b = w4[k * 64 + lane];
    sacc += a.x * b.x + a.y * b.y + a.z * b.z + a.w * b.w;
  }
  #pragma unroll
  for (int o = 32; o >= 1; o >>= 1) sacc += __shfl_xor(sacc, o);
  if (lane == 0) out[g] = sacc + bout[0];
}

// ---------------- launch ----------------
extern "C" void kernel_launch(void* const* d_in, const int* in_sizes, int n_in,
                              void* d_out, int out_size, void* d_ws, size_t ws_size,
                              hipStream_t stream) {
  const float* x   = (const float*)d_in[0];
  const int*   ei  = (const int*)d_in[1];
  const float* W1  = (const float*)d_in[2];
  const float* as1 = (const float*)d_in[3];
  const float* ad1 = (const float*)d_in[4];
  const float* b1  = (const float*)d_in[5];
  const float* W2  = (const float*)d_in[6];
  const float* as2 = (const float*)d_in[7];
  const float* ad2 = (const float*)d_in[8];
  const float* b2  = (const float*)d_in[9];
  const float* Wo  = (const float*)d_in[10];
  const float* bo  = (const float*)d_in[11];
  float* out = (float*)d_out;

  const int N = in_sizes[0] / F;
  const int E = in_sizes[1] / 2;
  const int* esrc = ei;
  const int* edst = ei + E;

  size_t off = 0;
  auto alloc = [&](size_t bytes) -> void* {
    void* p = (char*)d_ws + off;
    off += (bytes + 255) & ~(size_t)255;
    return p;
  };
  float* A    = (float*)alloc((size_t)N * F * 4);           // A1(bf16)/A2(fp32); CSR cnt/pos scratch aliases head
  unsigned short* hgb = (unsigned short*)alloc((size_t)N * F * 2);  // bf16 gemm outputs; binned aliases head
  float* als  = (float*)alloc((size_t)N * 4);
  float* ald  = (float*)alloc((size_t)N * 4);
  int* offs   = (int*)alloc((size_t)(N + 1) * 4);
  int* bsums  = (int*)alloc(8192);
  int* ssrc   = (int*)alloc((size_t)(E + N) * 4);           // CSR src lists
  (void)ws_size; (void)n_in; (void)out_size;

  const int NBLK = 256;                         // full-GPU edge passes
  const int NB = (N + NPB - 1) / NPB;           // 1024 buckets
  const int CH = (E + NBLK - 1) / NBLK;
  const int FLAT = NB * NBLK;                   // 262144

  int* cntT = (int*)A;
  int* posT = (int*)((char*)A + ((size_t)FLAT * 4 + 1024));
  unsigned int* binned = (unsigned int*)hgb;   // E uints <= N*F*2 bytes; dead before k_gemm writes hgb

  int gF = (FLAT + 255) / 256;

  // CSR build: bucketed counting sort (dst-major), self-loop at row head
  k_bin_count<<<NBLK, 256, 0, stream>>>(edst, cntT, E, CH, NBLK, NB);
  k_scan1<<<gF, 256, 0, stream>>>(cntT, posT, bsums, FLAT);
  k_scan2<<<1, 256, 0, stream>>>(bsums, gF);
  k_bin_scatter<<<NBLK, 256, 0, stream>>>(esrc, edst, posT, bsums, binned, E, CH, NBLK, NB);
  k_bucket_csr<<<NB, 256, 0, stream>>>(binned, posT, bsums, ssrc, offs, N, NBLK, NB, E);

  int gSp = (N + 31) / 32;   // 8 nodes/wave x 4 waves/block, exact cover
  // layer 1
  k_gemm<false><<<2560, 256, 0, stream>>>(x, W1, as1, ad1, hgb, als, ald, N);
  k_spmm<true><<<gSp, 256, 0, stream>>>(offs, ssrc, hgb, als, ald, b1, A, N);
  // layer 2 (reads bf16 A1)
  k_gemm<true><<<2560, 256, 0, stream>>>(A, W2, as2, ad2, hgb, als, ald, N);
  k_spmm<false><<<gSp, 256, 0, stream>>>(offs, ssrc, hgb, als, ald, b2, A, N);
  // readout
  int NG = N / 20;
  k_final<<<(NG + 3) / 4, 256, 0, stream>>>(A, Wo, bo, out, NG);
}